// Round 3
// baseline (2227.308 us; speedup 1.0000x reference)
//
#include <hip/hip_runtime.h>

// receptive_attention: out[b,h,i,j] = (|i-j| <= 128) ? dot(q[i,:], k[j,:]) : 0
// B=2 H=16 L=2048 D=64 fp32.
//
// R2: two sequential kernels, only measured-fast memory patterns.
//  1) zero_kernel: linear grid-stride float4 nontemporal stores over all 537 MB
//     (mimics harness fillBufferAligned, measured 6.25 TB/s on this buffer).
//  2) band_kernel: one 256-thread block per 64x64 band tile (|ti-tj|<=2).
//     K staged TRANSPOSED in LDS -> Q and K fragment reads are float4 with
//     broadcast/2-way bank aliasing (free per m136); stores are contiguous
//     256 B per row float4 nt stores, overwriting the zeros (same stream ->
//     ordered, no race).
// R1's fused structure measured 9x HBM traffic amplification (FETCH 1.7 GB /
// WRITE 3.2 GB) with no source-level mechanism -> abandoned.

typedef float v4f __attribute__((ext_vector_type(4)));

constexpr int L = 2048;
constexpr int D = 64;
constexpr int R = 128;
constexpr int TILE = 64;
constexpr int NT = L / TILE;   // 32
constexpr int KS  = D + 4;     // 68 dwords: Qs row stride (16B-aligned rows)
constexpr int KSJ = D + 4;     // 68 dwords: Kt row stride

__global__ __launch_bounds__(256)
void zero_kernel(v4f* __restrict__ out, int n4) {
    const v4f z = {0.f, 0.f, 0.f, 0.f};
    int idx = blockIdx.x * 256 + threadIdx.x;
    const int stride = gridDim.x * 256;
    for (int i = idx; i < n4; i += stride)
        __builtin_nontemporal_store(z, out + i);
}

__global__ __launch_bounds__(256, 4)
void band_kernel(const float* __restrict__ q, const float* __restrict__ k,
                 float* __restrict__ out) {
    const int ti = blockIdx.x;
    const int tj = ti + (int)blockIdx.y - 2;
    if (tj < 0 || tj >= NT) return;
    const int bh = blockIdx.z;
    const int t  = threadIdx.x;

    __shared__ float Qs[TILE * KS];   // Qs[i][d], row-major
    __shared__ float Kt[D * KSJ];     // Kt[d][j], transposed

    const float* qT = q + ((size_t)bh * L + (size_t)ti * TILE) * D;
    const float* kT = k + ((size_t)bh * L + (size_t)tj * TILE) * D;

    // Stage: coalesced float4 global loads; Q stored row-major (aligned v4f
    // LDS write), K scattered transposed (4 scalar LDS writes, one-time cost).
    #pragma unroll
    for (int it = 0; it < 4; ++it) {
        int idx = t + it * 256;
        int row = idx >> 4, col = (idx & 15) * 4;
        v4f qv = *reinterpret_cast<const v4f*>(qT + row * D + col);
        v4f kv = *reinterpret_cast<const v4f*>(kT + row * D + col);
        *reinterpret_cast<v4f*>(&Qs[row * KS + col]) = qv;
        #pragma unroll
        for (int c = 0; c < 4; ++c)
            Kt[(col + c) * KSJ + row] = kv[c];
    }
    __syncthreads();

    const int a = t >> 4;   // rows a + 16*rr  (0..15)
    const int b = t & 15;   // cols 4*b + cc   (0..15)

    // Q read: address depends only on a -> 16-lane broadcast, free.
    // Kt read: 16 consecutive float4 per wave -> 2-way bank alias, free.
    float acc[4][4] = {};
    #pragma unroll
    for (int dg = 0; dg < 16; ++dg) {
        v4f qa[4], kb[4];
        #pragma unroll
        for (int rr = 0; rr < 4; ++rr)
            qa[rr] = *reinterpret_cast<const v4f*>(&Qs[(a + 16 * rr) * KS + 4 * dg]);
        #pragma unroll
        for (int dd = 0; dd < 4; ++dd)
            kb[dd] = *reinterpret_cast<const v4f*>(&Kt[(4 * dg + dd) * KSJ + 4 * b]);
        #pragma unroll
        for (int rr = 0; rr < 4; ++rr) {
            #pragma unroll
            for (int cc = 0; cc < 4; ++cc) {
                acc[rr][cc] += qa[rr][0] * kb[0][cc] + qa[rr][1] * kb[1][cc]
                             + qa[rr][2] * kb[2][cc] + qa[rr][3] * kb[3][cc];
            }
        }
    }

    // Store: per wave-instruction 4 rows x 256 B fully contiguous, nt.
    const int i0 = ti * TILE, j0 = tj * TILE;
    float* outT = out + (size_t)bh * L * L + (size_t)i0 * L + j0;
    #pragma unroll
    for (int rr = 0; rr < 4; ++rr) {
        const int row = a + 16 * rr;
        const int gi  = i0 + row;
        v4f v;
        #pragma unroll
        for (int cc = 0; cc < 4; ++cc) {
            int gj = j0 + 4 * b + cc;
            int diff = gi - gj; if (diff < 0) diff = -diff;
            v[cc] = (diff <= R) ? acc[rr][cc] : 0.f;
        }
        __builtin_nontemporal_store(
            v, reinterpret_cast<v4f*>(outT + (size_t)row * L + 4 * b));
    }
}

extern "C" void kernel_launch(void* const* d_in, const int* in_sizes, int n_in,
                              void* d_out, int out_size, void* d_ws, size_t ws_size,
                              hipStream_t stream) {
    const float* q = (const float*)d_in[0];
    const float* k = (const float*)d_in[1];
    float* out = (float*)d_out;

    const int n4 = out_size / 4;                 // 33,554,432 float4
    zero_kernel<<<2048, 256, 0, stream>>>((v4f*)out, n4);

    dim3 grid(NT, 5, 32);                        // tj = ti + y - 2, clipped
    band_kernel<<<grid, 256, 0, stream>>>(q, k, out);
}

// Round 4
// 553.233 us; speedup vs baseline: 4.0260x; 4.0260x over previous
//
#include <hip/hip_runtime.h>

// receptive_attention: out[b,h,i,j] = (|i-j| <= 128) ? dot(q[i,:], k[j,:]) : 0
// B=2 H=16 L=2048 D=64 fp32.
//
// R3: single dispatch (R0 structure, best measured: 215 us), two block kinds:
//  - band blocks (y=0..4): R0's verbatim 64x64 tile path — LDS stride-65
//    staging, 4x4 fp32 micro-tile, masked PLAIN float4 stores.
//  - zero blocks (y=5..8): per-strip complement of the band-tile region is
//    64-col aligned -> each row's zeros are two contiguous runs (up to
//    7.5 KB). 16 rows per block, row-linear float4 sweeps (fill-like bursts,
//    which measured 6.25 TB/s) instead of R0's 256 B-at-8KB-stride pattern.
// MEASURED-BAD, do not reintroduce: __builtin_nontemporal_store (R2: 2x slower
// linear fill; 35x FETCH+WRITE RMW amplification on tile stores) and
// transposed-K LDS staging (8-way write conflicts, 4.4M SQ_LDS_BANK_CONFLICT).

constexpr int L = 2048;
constexpr int D = 64;
constexpr int R = 128;
constexpr int TILE = 64;
constexpr int NT = L / TILE;        // 32
constexpr int KS = D + 1;           // 65: R0's conflict profile

__global__ __launch_bounds__(256, 4)
void receptive_attention_kernel(const float* __restrict__ q,
                                const float* __restrict__ k,
                                float* __restrict__ out) {
    const int ti   = blockIdx.x;    // 64-row strip
    const int kind = blockIdx.y;    // 0..4 band tile, 5..8 zero segment
    const int bh   = blockIdx.z;
    const int t    = threadIdx.x;

    const int jt_lo = (ti - 2 > 0) ? (ti - 2) : 0;
    const int jt_hi = (ti + 2 < NT - 1) ? (ti + 2) : (NT - 1);

    float* outStrip = out + (size_t)bh * L * L + (size_t)ti * TILE * L;

    __shared__ float Qs[TILE * KS];
    __shared__ float Ks[TILE * KS];

    if (kind >= 5) {
        // ---- zero block: rows [16*(kind-5), +16), row-linear runs ----
        const int r0  = (kind - 5) * 16;
        const int wl4 = (jt_lo * TILE) / 4;                  // left-run float4s
        const int rb  = (jt_hi + 1) * TILE;                  // right-run start col
        const int nz4 = (L - (jt_hi - jt_lo + 1) * TILE) / 4;
        const float4 z = make_float4(0.f, 0.f, 0.f, 0.f);
        for (int r = 0; r < 16; ++r) {
            float* orow = outStrip + (size_t)(r0 + r) * L;
            for (int f = t; f < nz4; f += 256) {
                int col = (f < wl4) ? (f * 4) : (rb + (f - wl4) * 4);
                *reinterpret_cast<float4*>(orow + col) = z;
            }
        }
        return;
    }

    // ---- band tile block: tj = ti + kind - 2 (R0 path, verbatim) ----
    const int tj = ti + kind - 2;
    if (tj < 0 || tj >= NT) return;

    const float* qTile = q + ((size_t)bh * L + (size_t)ti * TILE) * D;
    const float* kTile = k + ((size_t)bh * L + (size_t)tj * TILE) * D;

    #pragma unroll
    for (int it = 0; it < 4; ++it) {
        int idx = t + it * 256;
        int row = idx >> 4;
        int col = (idx & 15) * 4;
        float4 qv = *reinterpret_cast<const float4*>(qTile + row * D + col);
        float4 kv = *reinterpret_cast<const float4*>(kTile + row * D + col);
        float* qd = &Qs[row * KS + col];
        qd[0] = qv.x; qd[1] = qv.y; qd[2] = qv.z; qd[3] = qv.w;
        float* kd = &Ks[row * KS + col];
        kd[0] = kv.x; kd[1] = kv.y; kd[2] = kv.z; kd[3] = kv.w;
    }
    __syncthreads();

    const int tr = (t >> 4) * 4;   // micro-tile base row
    const int tc = (t & 15) * 4;   // micro-tile base col

    float acc[4][4] = {};
    #pragma unroll 8
    for (int d = 0; d < D; ++d) {
        float a0 = Qs[(tr + 0) * KS + d];
        float a1 = Qs[(tr + 1) * KS + d];
        float a2 = Qs[(tr + 2) * KS + d];
        float a3 = Qs[(tr + 3) * KS + d];
        float b0 = Ks[(tc + 0) * KS + d];
        float b1 = Ks[(tc + 1) * KS + d];
        float b2 = Ks[(tc + 2) * KS + d];
        float b3 = Ks[(tc + 3) * KS + d];
        acc[0][0] += a0 * b0; acc[0][1] += a0 * b1; acc[0][2] += a0 * b2; acc[0][3] += a0 * b3;
        acc[1][0] += a1 * b0; acc[1][1] += a1 * b1; acc[1][2] += a1 * b2; acc[1][3] += a1 * b3;
        acc[2][0] += a2 * b0; acc[2][1] += a2 * b1; acc[2][2] += a2 * b2; acc[2][3] += a2 * b3;
        acc[3][0] += a3 * b0; acc[3][1] += a3 * b1; acc[3][2] += a3 * b2; acc[3][3] += a3 * b3;
    }

    float* outTile = outStrip + tj * TILE;
    const int gi0 = ti * TILE + tr;
    const int gj0 = tj * TILE + tc;
    #pragma unroll
    for (int rr = 0; rr < 4; ++rr) {
        int gi = gi0 + rr;
        float4 v;
        float* vp = &v.x;
        #pragma unroll
        for (int cc = 0; cc < 4; ++cc) {
            int gj = gj0 + cc;
            int diff = gi - gj;
            if (diff < 0) diff = -diff;
            vp[cc] = (diff <= R) ? acc[rr][cc] : 0.f;
        }
        *reinterpret_cast<float4*>(outTile + (size_t)(tr + rr) * L + tc) = v;
    }
}

extern "C" void kernel_launch(void* const* d_in, const int* in_sizes, int n_in,
                              void* d_out, int out_size, void* d_ws, size_t ws_size,
                              hipStream_t stream) {
    const float* q = (const float*)d_in[0];
    const float* k = (const float*)d_in[1];
    float* out = (float*)d_out;

    dim3 grid(NT, 9, 32);   // x=strip, y=0..4 band tiles / 5..8 zero rows, z=bh
    receptive_attention_kernel<<<grid, 256, 0, stream>>>(q, k, out);
}